// Round 20
// baseline (131.192 us; speedup 1.0000x reference)
//
#include <hip/hip_runtime.h>
#include <cstdint>
#include <cfloat>
#include <cmath>

#define NPTS 65536
#define NB 16
#define NS 20
#define KK 10
#define FPB 16      // FPS blocks per batch
#define NSm1 (NS - 1)
#define SPW 69      // float4 slots per scan-wave (15 waves x 69 >= 1024)

struct InitIdx { int idx[NB]; };

static __device__ __forceinline__ unsigned long long
agent_ld(const unsigned long long* p) {
    return __hip_atomic_load(p, __ATOMIC_RELAXED, __HIP_MEMORY_SCOPE_AGENT);
}
static __device__ __forceinline__ unsigned int
agent_ld32(const unsigned int* p) {
    return __hip_atomic_load(p, __ATOMIC_RELAXED, __HIP_MEMORY_SCOPE_AGENT);
}

// ---- branchless sorted insert into an 11-list (independent med3 ops) -------
#define INS11(L, SQ)                                                     \
    {                                                                    \
        _Pragma("unroll")                                                \
        for (int jj = 10; jj >= 1; --jj)                                 \
            L[jj] = __builtin_amdgcn_fmed3f(L[jj - 1], L[jj], (SQ));     \
        L[0] = fminf(L[0], (SQ));                                        \
    }

// ---------------- Kernel: FPS with kNN hidden in the sync slack -------------
// 256 blocks (16/batch) x 1024 threads. FPS loop sync structure is
// R12-verbatim (46.5us, reproduced 5x). NEW: per step s, while wave 0 does
// the cross-block argmax exchange (publish + ~2us IC poll), waves 1-15 scan
// seed s's kNN over the block's LDS-staged 4096-pt slice (wave v owns 69
// contiguous float4 slots; <=8 pts/lane -> INS11; wave-pop-11 ->
// s_part[s][v-1]). ~0.3us of work hides inside the ~2us poll window (3x
// margin) -> the R19 post-phase (~17us) collapses into the loop. R7's fusion
// failed because the kNN sat ON the critical path (extra barrier, all
// waves); here wave 0's sync path is untouched.
// Post-loop: wave w merges seeds {w, w+16} (165 -> 11, R12-proven pop) and
// publishes 11 nonzero u32 keys (fbits+1); R19-verbatim tail polls 176 keys
// per pair, computes repulsion, atomicAdd. No deadlock: 256 blocks
// co-resident; every key written unconditionally before any tail poll.
__global__ __launch_bounds__(1024, 4) void fps_kernel(const float* __restrict__ pcs,
                                                      unsigned long long* __restrict__ fkey,
                                                      unsigned int* __restrict__ part,
                                                      float* __restrict__ out,
                                                      InitIdx init) {
    const int u   = blockIdx.x;
    const int xcd = u & 7;              // XCD heuristic (perf-only)
    const int k   = u >> 3;             // 0..31
    const int b   = 2 * xcd + (k >> 4); // batch
    const int j   = k & 15;             // block-in-batch
    const int t   = threadIdx.x;
    const int lane = t & 63;
    const int w    = t >> 6;
    const float* __restrict__ base = pcs + (size_t)b * NPTS * 3;
    const int pbase = j * 4096 + t * 4; // 4 contiguous points per thread

    const float4* q4 = reinterpret_cast<const float4*>(base + (size_t)pbase * 3);
    float4 A = q4[0], Bv = q4[1], Cv = q4[2];
    float x[4] = { A.x, A.w, Bv.z, Cv.y };
    float y[4] = { A.y, Bv.x, Bv.w, Cv.z };
    float z[4] = { A.z, Bv.y, Cv.x, Cv.w };
    float dm[4] = { 1e10f, 1e10f, 1e10f, 1e10f };

    __shared__ float s_val[16];
    __shared__ int   s_idx[16];
    __shared__ int   s_far;
    __shared__ int   s_seeds[NS];
    __shared__ float xs[4096];
    __shared__ float ys[4096];
    __shared__ float zs[4096];
    __shared__ float s_part[NS][15][11];   // per-step, per-scan-wave top-11

    // stage the slice registers -> LDS SoA (visibility covered by B1 of s=0)
    {
        float4* xv = reinterpret_cast<float4*>(xs);
        float4* yv = reinterpret_cast<float4*>(ys);
        float4* zv = reinterpret_cast<float4*>(zs);
        xv[t] = make_float4(x[0], x[1], x[2], x[3]);
        yv[t] = make_float4(y[0], y[1], y[2], y[3]);
        zv[t] = make_float4(z[0], z[1], z[2], z[3]);
    }

    int far = init.idx[b];

    for (int s = 0; s < NS; ++s) {
        if (t == 0) s_seeds[s] = far;                    // seed s BEFORE update

        if (s < NSm1) {
            const float* c = base + (size_t)far * 3;     // uniform, cached
            const float cx = c[0], cy = c[1], cz = c[2];

            float bestv = -1.0f;
            int   besti = 0;
#pragma unroll
            for (int q = 0; q < 4; ++q) {
                // match XLA: rounded sub/mul, sequential adds, NO fma
                float dx = __fsub_rn(x[q], cx);
                float dy = __fsub_rn(y[q], cy);
                float dz = __fsub_rn(z[q], cz);
                float d  = __fadd_rn(__fadd_rn(__fmul_rn(dx, dx), __fmul_rn(dy, dy)),
                                     __fmul_rn(dz, dz));
                dm[q] = fminf(dm[q], d);
                // q ascending = index ascending; strict > = first occurrence
                if (dm[q] > bestv) { bestv = dm[q]; besti = pbase + q; }
            }
#pragma unroll
            for (int off = 32; off >= 1; off >>= 1) {
                float ov = __shfl_down(bestv, off);
                int   oi = __shfl_down(besti, off);
                if (ov > bestv || (ov == bestv && oi < besti)) { bestv = ov; besti = oi; }
            }
            if (lane == 0) { s_val[w] = bestv; s_idx[w] = besti; }
        }
        __syncthreads();                                 // B1

        if (w == 0) {
            if (s < NSm1) {
                // parallel 16-lane block reduce -> packed key -> publish
                unsigned long long kv = 0ULL;
                if (lane < 16) {
                    kv = ((unsigned long long)__float_as_uint(s_val[lane]) << 32) |
                         (unsigned long long)(0xFFFFFFFFu - (unsigned int)s_idx[lane]);
                }
#pragma unroll
                for (int off = 8; off >= 1; off >>= 1) {
                    unsigned int lo = (unsigned int)kv, hi = (unsigned int)(kv >> 32);
                    unsigned int olo = (unsigned int)__shfl_xor((int)lo, off);
                    unsigned int ohi = (unsigned int)__shfl_xor((int)hi, off);
                    unsigned long long o = ((unsigned long long)ohi << 32) | olo;
                    if (o > kv) kv = o;
                }
                unsigned long long* fp = fkey + (size_t)(b * NS + s) * FPB;
                if (lane == 0)
                    __hip_atomic_store(&fp[j], kv, __ATOMIC_RELAXED,
                                       __HIP_MEMORY_SCOPE_AGENT);

                // 3-deep pipelined poll (lane l watches slot l&15)
                const unsigned long long* sl = fp + (lane & 15);
                unsigned long long p0 = agent_ld(sl);
                unsigned long long p1 = agent_ld(sl);
                unsigned long long p2 = agent_ld(sl);
                unsigned long long v;
                for (;;) {
                    if (!__any(p0 == 0ULL)) { v = p0; break; }
                    p0 = agent_ld(sl);
                    if (!__any(p1 == 0ULL)) { v = p1; break; }
                    p1 = agent_ld(sl);
                    if (!__any(p2 == 0ULL)) { v = p2; break; }
                    p2 = agent_ld(sl);
                }
#pragma unroll
                for (int off = 32; off >= 1; off >>= 1) {
                    unsigned int lo = (unsigned int)v, hi = (unsigned int)(v >> 32);
                    unsigned int olo = (unsigned int)__shfl_xor((int)lo, off);
                    unsigned int ohi = (unsigned int)__shfl_xor((int)hi, off);
                    unsigned long long o = ((unsigned long long)ohi << 32) | olo;
                    if (o > v) v = o;
                }
                if (lane == 0)
                    s_far = (int)(0xFFFFFFFFu - (unsigned int)(v & 0xFFFFFFFFull));
            }
        } else {
            // ---- kNN scan for seed s over this wave's LDS partition --------
            const int sidx = s_seeds[s];
            const float ccx = base[(size_t)sidx * 3 + 0];
            const float ccy = base[(size_t)sidx * 3 + 1];
            const float ccz = base[(size_t)sidx * 3 + 2];

            float lst[11];
#pragma unroll
            for (int jj = 0; jj < 11; ++jj) lst[jj] = FLT_MAX;

            const int Astart = (w - 1) * SPW;
            const int Aend   = (Astart + SPW < 1024) ? Astart + SPW : 1024;
            const float4* xv = reinterpret_cast<const float4*>(xs);
            const float4* yv = reinterpret_cast<const float4*>(ys);
            const float4* zv = reinterpret_cast<const float4*>(zs);
#pragma unroll
            for (int it = 0; it < 2; ++it) {
                const int p4 = Astart + it * 64 + lane;
                if (p4 < Aend) {
                    float4 qx = xv[p4], qy = yv[p4], qz = zv[p4];
                    float px[4] = { qx.x, qx.y, qx.z, qx.w };
                    float py[4] = { qy.x, qy.y, qy.z, qy.w };
                    float pz[4] = { qz.x, qz.y, qz.z, qz.w };
#pragma unroll
                    for (int q = 0; q < 4; ++q) {
                        float dx = __fsub_rn(px[q], ccx);
                        float dy = __fsub_rn(py[q], ccy);
                        float dz = __fsub_rn(pz[q], ccz);
                        float sq = __fadd_rn(__fadd_rn(__fmul_rn(dx, dx),
                                                       __fmul_rn(dy, dy)),
                                             __fmul_rn(dz, dz));
                        INS11(lst, sq);
                    }
                }
            }
            // wave-pop 11 into s_part[s][w-1]
            float* dst = &s_part[s][w - 1][0];
            for (int r = 0; r < 11; ++r) {
                float v = lst[0];
#pragma unroll
                for (int off = 32; off >= 1; off >>= 1) v = fminf(v, __shfl_xor(v, off));
                unsigned long long m = __ballot(lst[0] == v);
                if (lane == (int)__ffsll(m) - 1) {
#pragma unroll
                    for (int jj = 0; jj < 10; ++jj) lst[jj] = lst[jj + 1];
                    lst[10] = FLT_MAX;
                }
                if (lane == 0) dst[r] = v;
            }
        }
        __syncthreads();                                 // B2
        if (s < NSm1) far = s_far;
    }

    // ---- merges: wave w merges seeds {w, w+16}: 165 -> 11, publish keys ----
#pragma unroll
    for (int pass = 0; pass < 2; ++pass) {
        const int s2 = w + pass * 16;
        if (s2 >= NS) break;                 // wave-uniform
        const float* flat = &s_part[s2][0][0];   // 165 contiguous floats
        float a0 = flat[lane];
        float a1 = flat[lane + 64];
        float a2 = (lane + 128 < 165) ? flat[lane + 128] : FLT_MAX;
        unsigned int* pr = part + ((size_t)(b * NS + s2) * FPB + j) * 11;
        for (int r = 0; r < 11; ++r) {
            float mymin = fminf(a0, fminf(a1, a2));
            float v = mymin;
#pragma unroll
            for (int off = 32; off >= 1; off >>= 1) v = fminf(v, __shfl_xor(v, off));
            unsigned long long m = __ballot(mymin == v);
            if (lane == (int)__ffsll(m) - 1) {
                if (a0 == v)      a0 = FLT_MAX;
                else if (a1 == v) a1 = FLT_MAX;
                else              a2 = FLT_MAX;
            }
            if (lane == 0)
                __hip_atomic_store(&pr[r], __float_as_uint(v) + 1u,
                                   __ATOMIC_RELAXED, __HIP_MEMORY_SCOPE_AGENT);
        }
    }

    // ---- tail: block j merges seeds {j, j+16}: poll 176 keys, top-11, loss -
    for (int s2 = j; s2 < NS; s2 += FPB) {
        if (w == 0) {
            const unsigned int* sl2 = part + (size_t)(b * NS + s2) * FPB * 11;
            unsigned int k0 = 0, k1 = 0, k2 = (lane + 128 < 176) ? 0u : 1u;
            do {
                if (k0 == 0) k0 = agent_ld32(&sl2[lane]);
                if (k1 == 0) k1 = agent_ld32(&sl2[lane + 64]);
                if (k2 == 0) k2 = agent_ld32(&sl2[lane + 128]);
            } while (__any(k0 == 0 || k1 == 0 || k2 == 0));
            float a0 = __uint_as_float(k0 - 1u);
            float a1 = __uint_as_float(k1 - 1u);
            float a2 = (lane + 128 < 176) ? __uint_as_float(k2 - 1u) : FLT_MAX;

            const float HH = (float)(0.01 * 0.01);     // JAX weak-typed H*H
            float acc = 0.0f;
#pragma unroll
            for (int r = 0; r < 11; ++r) {
                float mymin = fminf(a0, fminf(a1, a2));
                float v = mymin;
#pragma unroll
                for (int off = 32; off >= 1; off >>= 1) v = fminf(v, __shfl_xor(v, off));
                unsigned long long m = __ballot(mymin == v);
                if (lane == (int)__ffsll(m) - 1) {
                    if (a0 == v)      a0 = FLT_MAX;
                    else if (a1 == v) a1 = FLT_MAX;
                    else              a2 = FLT_MAX;
                }
                if (lane == 0 && r >= 1) {             // r==0 is self (dist 0)
                    float sq = v;
                    float dd = (sq == 0.0f) ? 0.0f : __fsqrt_rn(sq);
                    float q2 = __fmul_rn(dd, dd);
                    float wt = expf(__fdiv_rn(-q2, HH));
                    acc = __fadd_rn(acc, -__fmul_rn(dd, wt));
                }
            }
            if (lane == 0) atomicAdd(out, acc * 0.0625f);   // mean over B=16
        }
    }
}

// ---------------- Host: JAX threefry2x32 (partitionable mode) ---------------
static inline uint32_t rotl32(uint32_t x, uint32_t d) { return (x << d) | (x >> (32 - d)); }

static void tf2x32(uint32_t k0, uint32_t k1, uint32_t x0, uint32_t x1,
                   uint32_t& y0, uint32_t& y1) {
    const uint32_t ks[3] = { k0, k1, k0 ^ k1 ^ 0x1BD11BDAu };
    const uint32_t rotA[4] = { 13, 15, 26, 6 };
    const uint32_t rotB[4] = { 17, 29, 16, 24 };
    uint32_t v0 = x0 + ks[0], v1 = x1 + ks[1];
    for (int i = 0; i < 5; ++i) {
        const uint32_t* rot = (i % 2 == 0) ? rotA : rotB;
        for (int j = 0; j < 4; ++j) {
            v0 += v1;
            v1 = rotl32(v1, rot[j]);
            v1 ^= v0;
        }
        v0 += ks[(i + 1) % 3];
        v1 += ks[(i + 2) % 3] + (uint32_t)(i + 1);
    }
    y0 = v0; y1 = v1;
}

extern "C" void kernel_launch(void* const* d_in, const int* in_sizes, int n_in,
                              void* d_out, int out_size, void* d_ws, size_t ws_size,
                              hipStream_t stream) {
    const float* pcs = (const float*)d_in[0];
    float* out = (float*)d_out;

    // ws: [2048,43008) fps keys u64[16*20*16];
    //     [49152, 49152+16*20*16*11*4=274432) part keys u32 (poll-on-zero)
    unsigned long long* fkey = (unsigned long long*)((char*)d_ws + 2048);
    unsigned int* part       = (unsigned int*)((char*)d_ws + 49152);

    // jax.random.key(1) -> threefry key (0,1), partitionable mode:
    //   split foldlike: k2 = threefry((0,1),(0,1)) both words
    //   random_bits: counters (0,i), out = y0 ^ y1; randint span 2^16 -> mask
    uint32_t k2_0, k2_1;
    tf2x32(0u, 1u, 0u, 1u, k2_0, k2_1);
    InitIdx init;
    for (int i = 0; i < NB; ++i) {
        uint32_t y0, y1;
        tf2x32(k2_0, k2_1, 0u, (uint32_t)i, y0, y1);
        init.idx[i] = (int)((y0 ^ y1) & 0xFFFFu);
    }

    hipMemsetAsync((char*)d_ws + 2048, 0, 272384, stream);   // fkey + part
    hipMemsetAsync(d_out, 0, sizeof(float), stream);

    hipLaunchKernelGGL(fps_kernel, dim3(NB * FPB), dim3(1024), 0, stream,
                       pcs, fkey, part, out, init);
}

// Round 21
// 72.749 us; speedup vs baseline: 1.8033x; 1.8033x over previous
//
#include <hip/hip_runtime.h>
#include <cstdint>
#include <cfloat>
#include <cmath>

#define NPTS 65536
#define NB 16
#define NS 20
#define KK 10
#define FPB 16      // FPS blocks per batch
#define NSm1 (NS - 1)

struct InitIdx { int idx[NB]; };

static __device__ __forceinline__ unsigned long long
agent_ld(const unsigned long long* p) {
    return __hip_atomic_load(p, __ATOMIC_RELAXED, __HIP_MEMORY_SCOPE_AGENT);
}
static __device__ __forceinline__ unsigned int
agent_ld32(const unsigned int* p) {
    return __hip_atomic_load(p, __ATOMIC_RELAXED, __HIP_MEMORY_SCOPE_AGENT);
}

// ---- branchless sorted insert into an 11-list (independent med3 ops) -------
#define INS11(L, SQ)                                                     \
    {                                                                    \
        _Pragma("unroll")                                                \
        for (int jj = 10; jj >= 1; --jj)                                 \
            L[jj] = __builtin_amdgcn_fmed3f(L[jj - 1], L[jj], (SQ));     \
        L[0] = fminf(L[0], (SQ));                                        \
    }

// ---------------- Kernel: FPS loop (R12-verbatim) + LDS kNN + tail merge ----
// R19 REVERT (73.2us best). R20's "hide kNN in the sync slack" regressed to
// 131us: the per-step scan+wave-pop (~1-3us on waves 1-15, 4 waves/SIMD
// stacked) exceeds wave 0's ~2us poll window, so B2 waits on the scan —
// poll slack is NOT free issue capacity at that granularity.
// Structure: loop bit-identical to R12 (46.5us, reproduced 6x; ~2 IC round
// trips/step = near the structural latency floor for exact cross-CU FPS);
// post-phase stages the slice registers->LDS SoA and wave w selects top-11
// for seeds {w, w+16}; tail merges 176 keys/pair and accumulates the loss.
__global__ __launch_bounds__(1024, 4) void fps_kernel(const float* __restrict__ pcs,
                                                      unsigned long long* __restrict__ fkey,
                                                      unsigned int* __restrict__ part,
                                                      float* __restrict__ out,
                                                      InitIdx init) {
    const int u   = blockIdx.x;
    const int xcd = u & 7;              // XCD heuristic (perf-only)
    const int k   = u >> 3;             // 0..31
    const int b   = 2 * xcd + (k >> 4); // batch
    const int j   = k & 15;             // block-in-batch
    const int t   = threadIdx.x;
    const int lane = t & 63;
    const int w    = t >> 6;
    const float* __restrict__ base = pcs + (size_t)b * NPTS * 3;
    const int pbase = j * 4096 + t * 4; // 4 contiguous points per thread

    const float4* q4 = reinterpret_cast<const float4*>(base + (size_t)pbase * 3);
    float4 A = q4[0], Bv = q4[1], Cv = q4[2];
    float x[4] = { A.x, A.w, Bv.z, Cv.y };
    float y[4] = { A.y, Bv.x, Bv.w, Cv.z };
    float z[4] = { A.z, Bv.y, Cv.x, Cv.w };
    float dm[4] = { 1e10f, 1e10f, 1e10f, 1e10f };

    __shared__ float s_val[16];
    __shared__ int   s_idx[16];
    __shared__ int   s_far;
    __shared__ int   s_seeds[NS];
    __shared__ float xs[4096];
    __shared__ float ys[4096];
    __shared__ float zs[4096];

    int far = init.idx[b];

    for (int s = 0; s < NS; ++s) {
        if (t == 0) s_seeds[s] = far;                    // seed s BEFORE update
        if (s == NSm1) break;                            // last update unused

        const float* c = base + (size_t)far * 3;         // uniform, cached
        const float cx = c[0], cy = c[1], cz = c[2];

        float bestv = -1.0f;
        int   besti = 0;
#pragma unroll
        for (int q = 0; q < 4; ++q) {
            // match XLA: rounded sub/mul, sequential adds, NO fma contraction
            float dx = __fsub_rn(x[q], cx);
            float dy = __fsub_rn(y[q], cy);
            float dz = __fsub_rn(z[q], cz);
            float d  = __fadd_rn(__fadd_rn(__fmul_rn(dx, dx), __fmul_rn(dy, dy)),
                                 __fmul_rn(dz, dz));
            dm[q] = fminf(dm[q], d);
            // q ascending = index ascending; strict > keeps first occurrence
            if (dm[q] > bestv) { bestv = dm[q]; besti = pbase + q; }
        }
#pragma unroll
        for (int off = 32; off >= 1; off >>= 1) {
            float ov = __shfl_down(bestv, off);
            int   oi = __shfl_down(besti, off);
            if (ov > bestv || (ov == bestv && oi < besti)) { bestv = ov; besti = oi; }
        }
        if (lane == 0) { s_val[w] = bestv; s_idx[w] = besti; }
        __syncthreads();                                 // B1

        if (w == 0) {
            // parallel 16-lane block reduce -> packed key -> publish
            unsigned long long kv = 0ULL;
            if (lane < 16) {
                kv = ((unsigned long long)__float_as_uint(s_val[lane]) << 32) |
                     (unsigned long long)(0xFFFFFFFFu - (unsigned int)s_idx[lane]);
            }
#pragma unroll
            for (int off = 8; off >= 1; off >>= 1) {
                unsigned int lo = (unsigned int)kv, hi = (unsigned int)(kv >> 32);
                unsigned int olo = (unsigned int)__shfl_xor((int)lo, off);
                unsigned int ohi = (unsigned int)__shfl_xor((int)hi, off);
                unsigned long long o = ((unsigned long long)ohi << 32) | olo;
                if (o > kv) kv = o;
            }
            unsigned long long* fp = fkey + (size_t)(b * NS + s) * FPB;
            if (lane == 0)
                __hip_atomic_store(&fp[j], kv, __ATOMIC_RELAXED,
                                   __HIP_MEMORY_SCOPE_AGENT);

            // 3-deep pipelined poll of the 16 slots (lane l watches slot l&15)
            const unsigned long long* sl = fp + (lane & 15);
            unsigned long long p0 = agent_ld(sl);
            unsigned long long p1 = agent_ld(sl);
            unsigned long long p2 = agent_ld(sl);
            unsigned long long v;
            for (;;) {
                if (!__any(p0 == 0ULL)) { v = p0; break; }
                p0 = agent_ld(sl);
                if (!__any(p1 == 0ULL)) { v = p1; break; }
                p1 = agent_ld(sl);
                if (!__any(p2 == 0ULL)) { v = p2; break; }
                p2 = agent_ld(sl);
            }
#pragma unroll
            for (int off = 32; off >= 1; off >>= 1) {
                unsigned int lo = (unsigned int)v, hi = (unsigned int)(v >> 32);
                unsigned int olo = (unsigned int)__shfl_xor((int)lo, off);
                unsigned int ohi = (unsigned int)__shfl_xor((int)hi, off);
                unsigned long long o = ((unsigned long long)ohi << 32) | olo;
                if (o > v) v = o;
            }
            if (lane == 0)
                s_far = (int)(0xFFFFFFFFu - (unsigned int)(v & 0xFFFFFFFFull));
        }
        __syncthreads();                                 // B2
        far = s_far;
    }

    // ---- stage the slice registers -> LDS SoA (no global re-read) ----------
    {
        float4* xv = reinterpret_cast<float4*>(xs);
        float4* yv = reinterpret_cast<float4*>(ys);
        float4* zv = reinterpret_cast<float4*>(zs);
        xv[t] = make_float4(x[0], x[1], x[2], x[3]);
        yv[t] = make_float4(y[0], y[1], y[2], y[3]);
        zv[t] = make_float4(z[0], z[1], z[2], z[3]);
    }
    __syncthreads();   // s_seeds + LDS slice complete

    // ---- post-phase: wave w selects top-11 for seeds {w, w+16} from LDS ----
#pragma unroll
    for (int pass = 0; pass < 2; ++pass) {
        const int s2 = w + pass * 16;
        if (s2 >= NS) break;                 // wave-uniform
        const int sidx = s_seeds[s2];
        const float ccx = base[(size_t)sidx * 3 + 0];
        const float ccy = base[(size_t)sidx * 3 + 1];
        const float ccz = base[(size_t)sidx * 3 + 2];

        float lst[11];
#pragma unroll
        for (int jj = 0; jj < 11; ++jj) lst[jj] = FLT_MAX;

        const float4* xv = reinterpret_cast<const float4*>(xs);
        const float4* yv = reinterpret_cast<const float4*>(ys);
        const float4* zv = reinterpret_cast<const float4*>(zs);
        for (int i = 0; i < 16; ++i) {
            const int p4 = i * 64 + lane;    // float4 index, 0..1023
            float4 qx = xv[p4], qy = yv[p4], qz = zv[p4];
            float px[4] = { qx.x, qx.y, qx.z, qx.w };
            float py[4] = { qy.x, qy.y, qy.z, qy.w };
            float pz[4] = { qz.x, qz.y, qz.z, qz.w };
#pragma unroll
            for (int q = 0; q < 4; ++q) {
                float dx = __fsub_rn(px[q], ccx);
                float dy = __fsub_rn(py[q], ccy);
                float dz = __fsub_rn(pz[q], ccz);
                float sq = __fadd_rn(__fadd_rn(__fmul_rn(dx, dx), __fmul_rn(dy, dy)),
                                     __fmul_rn(dz, dz));
                INS11(lst, sq);
            }
        }
        // wave-pop 11; lane0 publishes nonzero keys (fbits+1, monotone)
        unsigned int* pr = part + ((size_t)(b * NS + s2) * FPB + j) * 11;
        for (int r = 0; r < 11; ++r) {
            float v = lst[0];
#pragma unroll
            for (int off = 32; off >= 1; off >>= 1) v = fminf(v, __shfl_xor(v, off));
            unsigned long long m = __ballot(lst[0] == v);
            if (lane == (int)__ffsll(m) - 1) {
#pragma unroll
                for (int jj = 0; jj < 10; ++jj) lst[jj] = lst[jj + 1];
                lst[10] = FLT_MAX;
            }
            if (lane == 0)
                __hip_atomic_store(&pr[r], __float_as_uint(v) + 1u,
                                   __ATOMIC_RELAXED, __HIP_MEMORY_SCOPE_AGENT);
        }
    }

    // ---- tail: block j merges seeds {j, j+16}: poll 176 keys, top-11, loss -
    for (int s2 = j; s2 < NS; s2 += FPB) {
        if (w == 0) {
            const unsigned int* sl2 = part + (size_t)(b * NS + s2) * FPB * 11;
            unsigned int k0 = 0, k1 = 0, k2 = (lane + 128 < 176) ? 0u : 1u;
            do {
                if (k0 == 0) k0 = agent_ld32(&sl2[lane]);
                if (k1 == 0) k1 = agent_ld32(&sl2[lane + 64]);
                if (k2 == 0) k2 = agent_ld32(&sl2[lane + 128]);
            } while (__any(k0 == 0 || k1 == 0 || k2 == 0));
            float a0 = __uint_as_float(k0 - 1u);
            float a1 = __uint_as_float(k1 - 1u);
            float a2 = (lane + 128 < 176) ? __uint_as_float(k2 - 1u) : FLT_MAX;

            const float HH = (float)(0.01 * 0.01);     // JAX weak-typed H*H
            float acc = 0.0f;
#pragma unroll
            for (int r = 0; r < 11; ++r) {
                float mymin = fminf(a0, fminf(a1, a2));
                float v = mymin;
#pragma unroll
                for (int off = 32; off >= 1; off >>= 1) v = fminf(v, __shfl_xor(v, off));
                unsigned long long m = __ballot(mymin == v);
                if (lane == (int)__ffsll(m) - 1) {
                    if (a0 == v)      a0 = FLT_MAX;
                    else if (a1 == v) a1 = FLT_MAX;
                    else              a2 = FLT_MAX;
                }
                if (lane == 0 && r >= 1) {             // r==0 is self (dist 0)
                    float sq = v;
                    float dd = (sq == 0.0f) ? 0.0f : __fsqrt_rn(sq);
                    float q2 = __fmul_rn(dd, dd);
                    float wt = expf(__fdiv_rn(-q2, HH));
                    acc = __fadd_rn(acc, -__fmul_rn(dd, wt));
                }
            }
            if (lane == 0) atomicAdd(out, acc * 0.0625f);   // mean over B=16
        }
    }
}

// ---------------- Host: JAX threefry2x32 (partitionable mode) ---------------
static inline uint32_t rotl32(uint32_t x, uint32_t d) { return (x << d) | (x >> (32 - d)); }

static void tf2x32(uint32_t k0, uint32_t k1, uint32_t x0, uint32_t x1,
                   uint32_t& y0, uint32_t& y1) {
    const uint32_t ks[3] = { k0, k1, k0 ^ k1 ^ 0x1BD11BDAu };
    const uint32_t rotA[4] = { 13, 15, 26, 6 };
    const uint32_t rotB[4] = { 17, 29, 16, 24 };
    uint32_t v0 = x0 + ks[0], v1 = x1 + ks[1];
    for (int i = 0; i < 5; ++i) {
        const uint32_t* rot = (i % 2 == 0) ? rotA : rotB;
        for (int j = 0; j < 4; ++j) {
            v0 += v1;
            v1 = rotl32(v1, rot[j]);
            v1 ^= v0;
        }
        v0 += ks[(i + 1) % 3];
        v1 += ks[(i + 2) % 3] + (uint32_t)(i + 1);
    }
    y0 = v0; y1 = v1;
}

extern "C" void kernel_launch(void* const* d_in, const int* in_sizes, int n_in,
                              void* d_out, int out_size, void* d_ws, size_t ws_size,
                              hipStream_t stream) {
    const float* pcs = (const float*)d_in[0];
    float* out = (float*)d_out;

    // ws: [2048,43008) fps keys u64[16*20*16];
    //     [49152, 49152+16*20*16*11*4=274432) part keys u32 (poll-on-zero)
    unsigned long long* fkey = (unsigned long long*)((char*)d_ws + 2048);
    unsigned int* part       = (unsigned int*)((char*)d_ws + 49152);

    // jax.random.key(1) -> threefry key (0,1), partitionable mode:
    //   split foldlike: k2 = threefry((0,1),(0,1)) both words
    //   random_bits: counters (0,i), out = y0 ^ y1; randint span 2^16 -> mask
    uint32_t k2_0, k2_1;
    tf2x32(0u, 1u, 0u, 1u, k2_0, k2_1);
    InitIdx init;
    for (int i = 0; i < NB; ++i) {
        uint32_t y0, y1;
        tf2x32(k2_0, k2_1, 0u, (uint32_t)i, y0, y1);
        init.idx[i] = (int)((y0 ^ y1) & 0xFFFFu);
    }

    // zero fkey + part in one call ([2048, 274432)); d_out separately
    hipMemsetAsync((char*)d_ws + 2048, 0, 272384, stream);
    hipMemsetAsync(d_out, 0, sizeof(float), stream);

    hipLaunchKernelGGL(fps_kernel, dim3(NB * FPB), dim3(1024), 0, stream,
                       pcs, fkey, part, out, init);
}